// Round 14
// baseline (321.143 us; speedup 1.0000x reference)
//
#include <hip/hip_runtime.h>
#include <math.h>

#define N_NODES 50000
#define N_EDGES 800000
#define IN_DIM 96
#define NHEADS 8
#define HDIM 12

#define QKV_BLOCKS 782   // ceil(50000/64)
#define HIST_BLOCKS 3125 // 800000/256
#define SCAN_BLOCKS 196  // ceil(50000/256)

typedef __attribute__((ext_vector_type(8))) short short8;
typedef __attribute__((ext_vector_type(4))) float f32x4;

__device__ __forceinline__ unsigned short f2bf(float f) {
    unsigned int u = __float_as_uint(f);
    return (unsigned short)((u + 0x7FFFu + ((u >> 16) & 1u)) >> 16);
}
__device__ __forceinline__ float bf2f_lo(unsigned int u) {
    return __uint_as_float(u << 16);
}
__device__ __forceinline__ float bf2f_hi(unsigned int u) {
    return __uint_as_float(u & 0xFFFF0000u);
}
__device__ __forceinline__ unsigned int pack2(float a, float b) {
    return (unsigned int)f2bf(a) | ((unsigned int)f2bf(b) << 16);
}
__device__ __forceinline__ short8 pack8(const float4 lo, const float4 hi) {
    union { uint4 u; short8 s; } c;
    c.u.x = pack2(lo.x, lo.y);
    c.u.y = pack2(lo.z, lo.w);
    c.u.z = pack2(hi.x, hi.y);
    c.u.w = pack2(hi.z, hi.w);
    return c.s;
}

// ---------------------------------------------------------------------------
// wet4: all four weights fp32 [96 in][96 out] -> bf16 transposed [96 out][96 in]
// ---------------------------------------------------------------------------
__global__ __launch_bounds__(256) void wet4_kernel(
    const float* __restrict__ Wq, const float* __restrict__ Wk,
    const float* __restrict__ Wv, const float* __restrict__ We,
    unsigned short* __restrict__ WqT, unsigned short* __restrict__ WkT,
    unsigned short* __restrict__ WvT, unsigned short* __restrict__ WeT)
{
    const int j = blockIdx.x * 256 + threadIdx.x;
    if (j >= 4 * 9216) return;
    const int m = j / 9216, r = j % 9216;
    const float* W = (m == 0) ? Wq : (m == 1) ? Wk : (m == 2) ? Wv : We;
    unsigned short* WT = (m == 0) ? WqT : (m == 1) ? WkT : (m == 2) ? WvT : WeT;
    const int k = r / 96, c = r % 96;
    WT[c * 96 + k] = f2bf(W[r]);
}

// ---------------------------------------------------------------------------
// Prep kernel: [0,782) Q/K/V MFMA projections; [782,3907) dst histogram.
// ---------------------------------------------------------------------------
__global__ __launch_bounds__(256) void prep_kernel(
    const float* __restrict__ x,
    const float* __restrict__ bq, const float* __restrict__ bk,
    const float* __restrict__ bv,
    const unsigned short* __restrict__ WqT, const unsigned short* __restrict__ WkT,
    const unsigned short* __restrict__ WvT,
    const int* __restrict__ ei,
    unsigned short* __restrict__ Qb, unsigned short* __restrict__ Kb,
    unsigned short* __restrict__ Vb,
    int* __restrict__ cursor)
{
    const int t = threadIdx.x;
    const int bid = blockIdx.x;

    if (bid >= QKV_BLOCKS) {
        const int e = (bid - QKV_BLOCKS) * 256 + t;
        if (e < N_EDGES) atomicAdd(&cursor[ei[N_EDGES + e]], 1);
        return;
    }

    const int wid = t >> 6;
    const int lid = t & 63;
    const int l15 = lid & 15;
    const int lg  = lid >> 4;
    const int nbase = bid * 64 + wid * 16;

    int arow = nbase + l15;
    if (arow >= N_NODES) arow = N_NODES - 1;
    const float* xr = &x[(size_t)arow * 96 + lg * 8];
    short8 af[3];
    af[0] = pack8(*(const float4*)(xr + 0),  *(const float4*)(xr + 4));
    af[1] = pack8(*(const float4*)(xr + 32), *(const float4*)(xr + 36));
    af[2] = pack8(*(const float4*)(xr + 64), *(const float4*)(xr + 68));

    #pragma unroll
    for (int m = 0; m < 3; ++m) {
        const unsigned short* WT = (m == 0) ? WqT : (m == 1) ? WkT : WvT;
        const float* bias_p      = (m == 0) ? bq  : (m == 1) ? bk  : bv;
        unsigned short* Ob       = (m == 0) ? Qb  : (m == 1) ? Kb  : Vb;

        f32x4 acc[6] = {};
        #pragma unroll
        for (int kk = 0; kk < 3; ++kk) {
            #pragma unroll
            for (int ct = 0; ct < 6; ++ct) {
                const short8 b = *(const short8*)&WT[(ct * 16 + l15) * 96 + kk * 32 + lg * 8];
                acc[ct] = __builtin_amdgcn_mfma_f32_16x16x32_bf16(af[kk], b, acc[ct], 0, 0, 0);
            }
        }
        #pragma unroll
        for (int ct = 0; ct < 6; ++ct) {
            const int col = ct * 16 + l15;
            const float bias = bias_p[col];
            #pragma unroll
            for (int r = 0; r < 4; ++r) {
                const int n = nbase + lg * 4 + r;
                if (n < N_NODES)
                    Ob[(size_t)n * 96 + col] = f2bf(acc[ct][r] + bias);
            }
        }
    }
}

// ---------------------------------------------------------------------------
// 3-level parallel scan (unchanged).
// ---------------------------------------------------------------------------
__global__ __launch_bounds__(256) void scanA_kernel(
    const int* __restrict__ cursor, int* __restrict__ partial)
{
    __shared__ int lds[256];
    const int t = threadIdx.x;
    const int idx = blockIdx.x * 256 + t;
    lds[t] = (idx < N_NODES) ? cursor[idx] : 0;
    __syncthreads();
    for (int off = 128; off > 0; off >>= 1) {
        if (t < off) lds[t] += lds[t + off];
        __syncthreads();
    }
    if (t == 0) partial[blockIdx.x] = lds[0];
}

__global__ __launch_bounds__(256) void scanB_kernel(
    int* __restrict__ partial, int* __restrict__ offsets)
{
    __shared__ int lds[256];
    const int t = threadIdx.x;
    const int v = (t < SCAN_BLOCKS) ? partial[t] : 0;
    lds[t] = v;
    __syncthreads();
    for (int off = 1; off < 256; off <<= 1) {
        const int u = (t >= off) ? lds[t - off] : 0;
        __syncthreads();
        lds[t] += u;
        __syncthreads();
    }
    if (t < SCAN_BLOCKS) partial[t] = lds[t] - v;   // exclusive
    if (t == 0) offsets[N_NODES] = N_EDGES;
}

__global__ __launch_bounds__(256) void scanC_kernel(
    int* __restrict__ cursor, const int* __restrict__ partial,
    int* __restrict__ offsets)
{
    __shared__ int lds[256];
    const int t = threadIdx.x;
    const int idx = blockIdx.x * 256 + t;
    const int v = (idx < N_NODES) ? cursor[idx] : 0;
    lds[t] = v;
    __syncthreads();
    for (int off = 1; off < 256; off <<= 1) {
        const int u = (t >= off) ? lds[t - off] : 0;
        __syncthreads();
        lds[t] += u;
        __syncthreads();
    }
    const int excl = lds[t] - v + partial[blockIdx.x];
    if (idx < N_NODES) {
        offsets[idx] = excl;
        cursor[idx] = excl;
    }
}

// ---------------------------------------------------------------------------
// eproj: pure streaming MFMA GEMM. E_proj = ea @ We + be -> ep_g bf16 [E,96].
// Per wave: 16 edges, A-frags global->reg, B from LDS-staged WsT, epb
// per-wave LDS, then perfectly coalesced 48 B/lane stores.
// ---------------------------------------------------------------------------
__global__ __launch_bounds__(256, 4) void eproj_kernel(
    const float* __restrict__ ea,
    const unsigned short* __restrict__ WeT,
    const float* __restrict__ be,
    unsigned short* __restrict__ ep_g)
{
    __shared__ unsigned short WsT[96 * 104];
    __shared__ unsigned short epb[4][16 * 104];
    __shared__ float bes[96];

    const int t = threadIdx.x;
    const int wid = t >> 6;
    const int lid = t & 63;
    const int l15 = lid & 15;
    const int lg  = lid >> 4;
    const long wbase = (long)blockIdx.x * 64 + wid * 16;

    // A-fragment loads
    const float* arow = &ea[(wbase + l15) * 96 + lg * 8];
    const float4 a0lo = *(const float4*)(arow + 0);
    const float4 a0hi = *(const float4*)(arow + 4);
    const float4 a1lo = *(const float4*)(arow + 32);
    const float4 a1hi = *(const float4*)(arow + 36);
    const float4 a2lo = *(const float4*)(arow + 64);
    const float4 a2hi = *(const float4*)(arow + 68);

    // stage WsT + bias
    for (int j = t; j < 96 * 12; j += 256) {
        const int c = j / 12, kc = j % 12;
        *(uint4*)&WsT[c * 104 + kc * 8] = *(const uint4*)&WeT[c * 96 + kc * 8];
    }
    if (t < 96) bes[t] = be[t];
    __syncthreads();

    const short8 af[3] = {pack8(a0lo, a0hi), pack8(a1lo, a1hi), pack8(a2lo, a2hi)};

    f32x4 acc[6] = {};
    #pragma unroll
    for (int kk = 0; kk < 3; ++kk) {
        #pragma unroll
        for (int ct = 0; ct < 6; ++ct) {
            const short8 b = *(const short8*)&WsT[(ct * 16 + l15) * 104 + kk * 32 + lg * 8];
            acc[ct] = __builtin_amdgcn_mfma_f32_16x16x32_bf16(af[kk], b, acc[ct], 0, 0, 0);
        }
    }
    unsigned short* myep = epb[wid];
    #pragma unroll
    for (int ct = 0; ct < 6; ++ct) {
        const int col = ct * 16 + l15;
        const float bias = bes[col];
        #pragma unroll
        for (int r = 0; r < 4; ++r)
            myep[(lg * 4 + r) * 104 + col] = f2bf(acc[ct][r] + bias);
    }
    // same-wave LDS write->read (no barrier); coalesced store 48 B/lane
    const int row = lid >> 2;          // 0..15
    const int ch  = lid & 3;           // 24-col chunk
    const unsigned short* s = &myep[row * 104 + ch * 24];
    unsigned short* d = &ep_g[(size_t)(wbase + row) * 96 + ch * 24];
    *(uint4*)(d + 0)  = *(const uint4*)(s + 0);
    *(uint4*)(d + 8)  = *(const uint4*)(s + 8);
    *(uint4*)(d + 16) = *(const uint4*)(s + 16);
}

// ---------------------------------------------------------------------------
// score_lite: pure latency machine. Wave = 8 edges x 8 heads, one
// (edge,head) per lane; no LDS, small VGPR -> max TLP.
//   ei (coalesced, lanes 0-15) -> shfl; K[src]/Q[dst] gathers; ep coalesced;
//   lane h==0 per edge: atomicAdd cursor -> CSR slot + sorted_src write;
//   dot(K*Q*E)/sqrt(12), clip, exp, bf16 score in CSR order.
// ---------------------------------------------------------------------------
__global__ __launch_bounds__(256) void score_lite_kernel(
    const int* __restrict__ ei,
    const unsigned short* __restrict__ ep_g,
    const unsigned short* __restrict__ Qb, const unsigned short* __restrict__ Kb,
    int* __restrict__ cursor,
    int* __restrict__ sorted_src,
    unsigned short* __restrict__ score_b)
{
    const int t = threadIdx.x;
    const int lid = t & 63;
    const long ebase = ((long)blockIdx.x * 4 + (t >> 6)) * 8;  // wave's 8 edges
    const int er = lid >> 3;     // edge 0..7
    const int h  = lid & 7;      // head

    // coalesced ei: lanes 0-7 src[i], lanes 8-15 dst[i-8]
    int v = 0;
    if (lid < 16)
        v = (lid < 8) ? ei[ebase + lid] : ei[N_EDGES + ebase + (lid - 8)];

    const int src = __shfl(v, er, 64);
    const int dst = __shfl(v, 8 + er, 64);

    // K/Q gathers + coalesced ep read
    const uint2* Kp = (const uint2*)&Kb[(size_t)src * 96 + h * 12];
    const uint2* Qp = (const uint2*)&Qb[(size_t)dst * 96 + h * 12];
    const uint2* Ep = (const uint2*)&ep_g[(ebase + er) * 96 + h * 12];
    const uint2 ka = Kp[0], kb_ = Kp[1], kc = Kp[2];
    const uint2 qa = Qp[0], qb_ = Qp[1], qc = Qp[2];
    const uint2 u0 = Ep[0], u1 = Ep[1], u2 = Ep[2];

    // CSR slot: lanes 0-7 atomically claim for their edge
    const int dstFor = __shfl(v, 8 + (lid & 7), 64);
    int posv = 0;
    if (lid < 8) {
        posv = atomicAdd(&cursor[dstFor], 1);
        sorted_src[posv] = v;            // v == src for lanes 0-7
    }
    const int pos = __shfl(posv, er, 64);

    float s = 0.f;
#define ACC3(KU, QU, EU) \
    s += bf2f_lo(KU) * bf2f_lo(QU) * bf2f_lo(EU) + \
         bf2f_hi(KU) * bf2f_hi(QU) * bf2f_hi(EU);
    ACC3(ka.x, qa.x, u0.x); ACC3(ka.y, qa.y, u0.y);
    ACC3(kb_.x, qb_.x, u1.x); ACC3(kb_.y, qb_.y, u1.y);
    ACC3(kc.x, qc.x, u2.x); ACC3(kc.y, qc.y, u2.y);
#undef ACC3
    s *= 0.2886751345948129f;  // 1/sqrt(12)
    s = fminf(fmaxf(s, -5.f), 5.f);
    score_b[(size_t)pos * 8 + h] = f2bf(__expf(s));
}

// ---------------------------------------------------------------------------
// Gather kernel: thread = (node, 24-col group g); bf16 scores. (unchanged)
// ---------------------------------------------------------------------------
__global__ __launch_bounds__(256) void gather_kernel(
    const int* __restrict__ offsets, const int* __restrict__ sorted_src,
    const unsigned short* __restrict__ score_b, const unsigned short* __restrict__ Vb,
    float* __restrict__ out)
{
    const int gid = blockIdx.x * 256 + threadIdx.x;
    if (gid >= N_NODES * 4) return;
    const int n = gid >> 2;
    const int g = gid & 3;           // cols g*24 .. g*24+23, heads 2g, 2g+1

    const int s0 = offsets[n];
    const int s1 = offsets[n + 1];

    float acc[24];
    #pragma unroll
    for (int i = 0; i < 24; ++i) acc[i] = 0.f;
    float z0 = 0.f, z1 = 0.f;

#define ACCUM(U0, U1, U2, SX, SY) \
    acc[0]  += SX * bf2f_lo(U0.x); acc[1]  += SX * bf2f_hi(U0.x); \
    acc[2]  += SX * bf2f_lo(U0.y); acc[3]  += SX * bf2f_hi(U0.y); \
    acc[4]  += SX * bf2f_lo(U0.z); acc[5]  += SX * bf2f_hi(U0.z); \
    acc[6]  += SX * bf2f_lo(U0.w); acc[7]  += SX * bf2f_hi(U0.w); \
    acc[8]  += SX * bf2f_lo(U1.x); acc[9]  += SX * bf2f_hi(U1.x); \
    acc[10] += SX * bf2f_lo(U1.y); acc[11] += SX * bf2f_hi(U1.y); \
    acc[12] += SY * bf2f_lo(U1.z); acc[13] += SY * bf2f_hi(U1.z); \
    acc[14] += SY * bf2f_lo(U1.w); acc[15] += SY * bf2f_hi(U1.w); \
    acc[16] += SY * bf2f_lo(U2.x); acc[17] += SY * bf2f_hi(U2.x); \
    acc[18] += SY * bf2f_lo(U2.y); acc[19] += SY * bf2f_hi(U2.y); \
    acc[20] += SY * bf2f_lo(U2.z); acc[21] += SY * bf2f_hi(U2.z); \
    acc[22] += SY * bf2f_lo(U2.w); acc[23] += SY * bf2f_hi(U2.w);

    int p = s0;
    for (; p + 2 <= s1; p += 2) {
        const int srcA = sorted_src[p];
        const int srcB = sorted_src[p + 1];
        const unsigned int sA = *(const unsigned int*)&score_b[(size_t)p * 8 + g * 2];
        const unsigned int sB = *(const unsigned int*)&score_b[(size_t)(p + 1) * 8 + g * 2];
        const float sAx = bf2f_lo(sA), sAy = bf2f_hi(sA);
        const float sBx = bf2f_lo(sB), sBy = bf2f_hi(sB);
        const uint4* VA = (const uint4*)&Vb[(size_t)srcA * 96 + g * 24];
        const uint4* VB = (const uint4*)&Vb[(size_t)srcB * 96 + g * 24];
        const uint4 a0 = VA[0], a1 = VA[1], a2 = VA[2];
        const uint4 b0 = VB[0], b1 = VB[1], b2 = VB[2];
        ACCUM(a0, a1, a2, sAx, sAy);
        ACCUM(b0, b1, b2, sBx, sBy);
        z0 += sAx + sBx;
        z1 += sAy + sBy;
    }
    if (p < s1) {
        const int srcA = sorted_src[p];
        const unsigned int sA = *(const unsigned int*)&score_b[(size_t)p * 8 + g * 2];
        const float sAx = bf2f_lo(sA), sAy = bf2f_hi(sA);
        const uint4* VA = (const uint4*)&Vb[(size_t)srcA * 96 + g * 24];
        const uint4 a0 = VA[0], a1 = VA[1], a2 = VA[2];
        ACCUM(a0, a1, a2, sAx, sAy);
        z0 += sAx;
        z1 += sAy;
    }
#undef ACCUM

    const float i0 = 1.f / (z0 + 1e-6f);
    const float i1 = 1.f / (z1 + 1e-6f);
    float o[24];
    #pragma unroll
    for (int k = 0; k < 24; ++k) o[k] = acc[k] * (k < 12 ? i0 : i1);
    float* dst = &out[(size_t)n * 96 + g * 24];
    #pragma unroll
    for (int k = 0; k < 6; ++k)
        *(float4*)&dst[k * 4] = make_float4(o[k*4], o[k*4+1], o[k*4+2], o[k*4+3]);
}

// ---------------------------------------------------------------------------
extern "C" void kernel_launch(void* const* d_in, const int* in_sizes, int n_in,
                              void* d_out, int out_size, void* d_ws, size_t ws_size,
                              hipStream_t stream) {
    const float* x  = (const float*)d_in[0];
    const int*   ei = (const int*)d_in[1];   // [2, E] int32 (JAX x64 disabled)
    const float* ea = (const float*)d_in[2];
    const float* Wq = (const float*)d_in[3];
    const float* bq = (const float*)d_in[4];
    const float* Wk = (const float*)d_in[5];
    const float* bk = (const float*)d_in[6];
    const float* We = (const float*)d_in[7];
    const float* be = (const float*)d_in[8];
    const float* Wv = (const float*)d_in[9];
    const float* bv = (const float*)d_in[10];

    float* out = (float*)d_out;

    // workspace (ws ≈ 1.2 GB per poison-fill evidence):
    // Qb | Kb | Vb | score_b | offsets | cursor | sorted_src | W*T | partial | ep_g
    const size_t nqkv = (size_t)N_NODES * 96;
    unsigned short* Qb = (unsigned short*)d_ws;
    unsigned short* Kb = Qb + nqkv;
    unsigned short* Vb = Kb + nqkv;
    unsigned short* score_b = Vb + nqkv;                     // [E,8] bf16
    int* offsets    = (int*)(score_b + (size_t)N_EDGES * 8); // [N+1]
    int* cursor     = offsets + (N_NODES + 1);               // [N]
    int* sorted_src = cursor + N_NODES;                      // [E]
    unsigned short* WeT = (unsigned short*)(sorted_src + N_EDGES);  // [96*96]
    unsigned short* WqT = WeT + 9216;
    unsigned short* WkT = WqT + 9216;
    unsigned short* WvT = WkT + 9216;
    int* partial = (int*)(WvT + 9216);                       // [256]
    unsigned short* ep_g = (unsigned short*)(partial + 256); // [E*96] bf16, 153.6 MB

    hipMemsetAsync(cursor, 0, N_NODES * sizeof(int), stream);

    wet4_kernel<<<dim3(144), 256, 0, stream>>>(
        Wq, Wk, Wv, We, WqT, WkT, WvT, WeT);

    prep_kernel<<<dim3(QKV_BLOCKS + HIST_BLOCKS), 256, 0, stream>>>(
        x, bq, bk, bv, WqT, WkT, WvT, ei, Qb, Kb, Vb, cursor);

    scanA_kernel<<<dim3(SCAN_BLOCKS), 256, 0, stream>>>(cursor, partial);
    scanB_kernel<<<dim3(1), 256, 0, stream>>>(partial, offsets);
    scanC_kernel<<<dim3(SCAN_BLOCKS), 256, 0, stream>>>(cursor, partial, offsets);

    eproj_kernel<<<dim3(N_EDGES / 64), 256, 0, stream>>>(ea, WeT, be, ep_g);

    score_lite_kernel<<<dim3(N_EDGES / 32), 256, 0, stream>>>(
        ei, ep_g, Qb, Kb, cursor, sorted_src, score_b);

    gather_kernel<<<dim3((N_NODES * 4 + 255) / 256), 256, 0, stream>>>(
        offsets, sorted_src, score_b, Vb, out);
}

// Round 15
// 239.041 us; speedup vs baseline: 1.3435x; 1.3435x over previous
//
#include <hip/hip_runtime.h>
#include <math.h>

#define N_NODES 50000
#define N_EDGES 800000
#define IN_DIM 96
#define NHEADS 8
#define HDIM 12

#define QKV_BLOCKS 782   // ceil(50000/64)
#define HIST_BLOCKS 3125 // 800000/256
#define SCAN_BLOCKS 196  // ceil(50000/256)
#define TPB 10           // tiles (64 edges) per score block
#define SCORE_GRID 1250  // 1250 * 10 * 64 = 800000

typedef __attribute__((ext_vector_type(8))) short short8;
typedef __attribute__((ext_vector_type(4))) float f32x4;

__device__ __forceinline__ unsigned short f2bf(float f) {
    unsigned int u = __float_as_uint(f);
    return (unsigned short)((u + 0x7FFFu + ((u >> 16) & 1u)) >> 16);
}
__device__ __forceinline__ float bf2f_lo(unsigned int u) {
    return __uint_as_float(u << 16);
}
__device__ __forceinline__ float bf2f_hi(unsigned int u) {
    return __uint_as_float(u & 0xFFFF0000u);
}
__device__ __forceinline__ unsigned int pack2(float a, float b) {
    return (unsigned int)f2bf(a) | ((unsigned int)f2bf(b) << 16);
}
__device__ __forceinline__ short8 pack8(const float4 lo, const float4 hi) {
    union { uint4 u; short8 s; } c;
    c.u.x = pack2(lo.x, lo.y);
    c.u.y = pack2(lo.z, lo.w);
    c.u.z = pack2(hi.x, hi.y);
    c.u.w = pack2(hi.z, hi.w);
    return c.s;
}

// ---------------------------------------------------------------------------
// wet4: all four weights fp32 [96 in][96 out] -> bf16 transposed [96 out][96 in]
// ---------------------------------------------------------------------------
__global__ __launch_bounds__(256) void wet4_kernel(
    const float* __restrict__ Wq, const float* __restrict__ Wk,
    const float* __restrict__ Wv, const float* __restrict__ We,
    unsigned short* __restrict__ WqT, unsigned short* __restrict__ WkT,
    unsigned short* __restrict__ WvT, unsigned short* __restrict__ WeT)
{
    const int j = blockIdx.x * 256 + threadIdx.x;
    if (j >= 4 * 9216) return;
    const int m = j / 9216, r = j % 9216;
    const float* W = (m == 0) ? Wq : (m == 1) ? Wk : (m == 2) ? Wv : We;
    unsigned short* WT = (m == 0) ? WqT : (m == 1) ? WkT : (m == 2) ? WvT : WeT;
    const int k = r / 96, c = r % 96;
    WT[c * 96 + k] = f2bf(W[r]);
}

// ---------------------------------------------------------------------------
// Prep kernel: [0,782) Q/K/V MFMA projections; [782,3907) dst histogram.
// ---------------------------------------------------------------------------
__global__ __launch_bounds__(256) void prep_kernel(
    const float* __restrict__ x,
    const float* __restrict__ bq, const float* __restrict__ bk,
    const float* __restrict__ bv,
    const unsigned short* __restrict__ WqT, const unsigned short* __restrict__ WkT,
    const unsigned short* __restrict__ WvT,
    const int* __restrict__ ei,
    unsigned short* __restrict__ Qb, unsigned short* __restrict__ Kb,
    unsigned short* __restrict__ Vb,
    int* __restrict__ cursor)
{
    const int t = threadIdx.x;
    const int bid = blockIdx.x;

    if (bid >= QKV_BLOCKS) {
        const int e = (bid - QKV_BLOCKS) * 256 + t;
        if (e < N_EDGES) atomicAdd(&cursor[ei[N_EDGES + e]], 1);
        return;
    }

    const int wid = t >> 6;
    const int lid = t & 63;
    const int l15 = lid & 15;
    const int lg  = lid >> 4;
    const int nbase = bid * 64 + wid * 16;

    int arow = nbase + l15;
    if (arow >= N_NODES) arow = N_NODES - 1;
    const float* xr = &x[(size_t)arow * 96 + lg * 8];
    short8 af[3];
    af[0] = pack8(*(const float4*)(xr + 0),  *(const float4*)(xr + 4));
    af[1] = pack8(*(const float4*)(xr + 32), *(const float4*)(xr + 36));
    af[2] = pack8(*(const float4*)(xr + 64), *(const float4*)(xr + 68));

    #pragma unroll
    for (int m = 0; m < 3; ++m) {
        const unsigned short* WT = (m == 0) ? WqT : (m == 1) ? WkT : WvT;
        const float* bias_p      = (m == 0) ? bq  : (m == 1) ? bk  : bv;
        unsigned short* Ob       = (m == 0) ? Qb  : (m == 1) ? Kb  : Vb;

        f32x4 acc[6] = {};
        #pragma unroll
        for (int kk = 0; kk < 3; ++kk) {
            #pragma unroll
            for (int ct = 0; ct < 6; ++ct) {
                const short8 b = *(const short8*)&WT[(ct * 16 + l15) * 96 + kk * 32 + lg * 8];
                acc[ct] = __builtin_amdgcn_mfma_f32_16x16x32_bf16(af[kk], b, acc[ct], 0, 0, 0);
            }
        }
        #pragma unroll
        for (int ct = 0; ct < 6; ++ct) {
            const int col = ct * 16 + l15;
            const float bias = bias_p[col];
            #pragma unroll
            for (int r = 0; r < 4; ++r) {
                const int n = nbase + lg * 4 + r;
                if (n < N_NODES)
                    Ob[(size_t)n * 96 + col] = f2bf(acc[ct][r] + bias);
            }
        }
    }
}

// ---------------------------------------------------------------------------
// 3-level parallel scan (unchanged).
// ---------------------------------------------------------------------------
__global__ __launch_bounds__(256) void scanA_kernel(
    const int* __restrict__ cursor, int* __restrict__ partial)
{
    __shared__ int lds[256];
    const int t = threadIdx.x;
    const int idx = blockIdx.x * 256 + t;
    lds[t] = (idx < N_NODES) ? cursor[idx] : 0;
    __syncthreads();
    for (int off = 128; off > 0; off >>= 1) {
        if (t < off) lds[t] += lds[t + off];
        __syncthreads();
    }
    if (t == 0) partial[blockIdx.x] = lds[0];
}

__global__ __launch_bounds__(256) void scanB_kernel(
    int* __restrict__ partial, int* __restrict__ offsets)
{
    __shared__ int lds[256];
    const int t = threadIdx.x;
    const int v = (t < SCAN_BLOCKS) ? partial[t] : 0;
    lds[t] = v;
    __syncthreads();
    for (int off = 1; off < 256; off <<= 1) {
        const int u = (t >= off) ? lds[t - off] : 0;
        __syncthreads();
        lds[t] += u;
        __syncthreads();
    }
    if (t < SCAN_BLOCKS) partial[t] = lds[t] - v;   // exclusive
    if (t == 0) offsets[N_NODES] = N_EDGES;
}

__global__ __launch_bounds__(256) void scanC_kernel(
    int* __restrict__ cursor, const int* __restrict__ partial,
    int* __restrict__ offsets)
{
    __shared__ int lds[256];
    const int t = threadIdx.x;
    const int idx = blockIdx.x * 256 + t;
    const int v = (idx < N_NODES) ? cursor[idx] : 0;
    lds[t] = v;
    __syncthreads();
    for (int off = 1; off < 256; off <<= 1) {
        const int u = (t >= off) ? lds[t - off] : 0;
        __syncthreads();
        lds[t] += u;
        __syncthreads();
    }
    const int excl = lds[t] - v + partial[blockIdx.x];
    if (idx < N_NODES) {
        offsets[idx] = excl;
        cursor[idx] = excl;
    }
}

// ---------------------------------------------------------------------------
// Score kernel — PERSISTENT blocks with cross-tile software pipelining.
// (round-12 configuration: the measured optimum, 239 µs total)
// 1250 blocks x 10 tiles. Per iteration (processing tile i):
//   MFMA(ea_i, regs) -> epb ; issue K/Q gathers + atomics for i+1 ;
//   issue ei/ea loads for i+2 ; score phase for i (K/Q arrived last iter).
// ---------------------------------------------------------------------------
__global__ __launch_bounds__(256, 2) void score_kernel(
    const float* __restrict__ ea,
    const int* __restrict__ ei,
    const unsigned short* __restrict__ WeT,  // [96 out][96 in] bf16
    const float* __restrict__ be,
    const unsigned short* __restrict__ Qb, const unsigned short* __restrict__ Kb,
    int* __restrict__ cursor,
    int* __restrict__ sorted_src,
    float* __restrict__ score_s)             // [E,8] in CSR slot order
{
    __shared__ unsigned short WsT[96 * 104];     // 19968 B
    __shared__ unsigned short epb[4][16 * 104];  // 13312 B, per-wave
    __shared__ float bes[96];

    const int t = threadIdx.x;
    const int wid = t >> 6;
    const int lid = t & 63;
    const int l15 = lid & 15;
    const int lg  = lid >> 4;
    const int er  = lid >> 3;    // edge-in-pass 0..7
    const int h   = lid & 7;     // head
    unsigned short* myep = epb[wid];
    const long t0 = (long)blockIdx.x * TPB;

#define LOAD_EI(V, TILE) do { \
    const long wb_ = (long)(TILE) * 64 + wid * 16; \
    (V) = 0; \
    if (lid < 32) (V) = (lid < 16) ? ei[wb_ + lid] : ei[N_EDGES + wb_ + (lid - 16)]; \
} while (0)

#define LOAD_EA(EA, TILE) do { \
    const float* ar_ = &ea[((long)(TILE) * 64 + wid * 16 + l15) * 96 + lg * 8]; \
    (EA)[0] = *(const float4*)(ar_ + 0);  (EA)[1] = *(const float4*)(ar_ + 4); \
    (EA)[2] = *(const float4*)(ar_ + 32); (EA)[3] = *(const float4*)(ar_ + 36); \
    (EA)[4] = *(const float4*)(ar_ + 64); (EA)[5] = *(const float4*)(ar_ + 68); \
} while (0)

#define ISSUE_GATHER(V, KQ, P0, P1) do { \
    const int s0_ = __shfl((V), er, 64); \
    const int d0_ = __shfl((V), 16 + er, 64); \
    const int s1_ = __shfl((V), 8 + er, 64); \
    const int d1_ = __shfl((V), 24 + er, 64); \
    const uint2* K0_ = (const uint2*)&Kb[(size_t)s0_ * 96 + h * 12]; \
    const uint2* Q0_ = (const uint2*)&Qb[(size_t)d0_ * 96 + h * 12]; \
    const uint2* K1_ = (const uint2*)&Kb[(size_t)s1_ * 96 + h * 12]; \
    const uint2* Q1_ = (const uint2*)&Qb[(size_t)d1_ * 96 + h * 12]; \
    (KQ)[0] = K0_[0]; (KQ)[1] = K0_[1]; (KQ)[2] = K0_[2]; \
    (KQ)[3] = Q0_[0]; (KQ)[4] = Q0_[1]; (KQ)[5] = Q0_[2]; \
    (KQ)[6] = K1_[0]; (KQ)[7] = K1_[1]; (KQ)[8] = K1_[2]; \
    (KQ)[9] = Q1_[0]; (KQ)[10] = Q1_[1]; (KQ)[11] = Q1_[2]; \
    const int md_ = __shfl((V), 16 + l15, 64); \
    int pv_ = 0; \
    if (lid < 16) { pv_ = atomicAdd(&cursor[md_], 1); sorted_src[pv_] = (V); } \
    (P0) = __shfl(pv_, er, 64); \
    (P1) = __shfl(pv_, 8 + er, 64); \
} while (0)

#define MFMA_EPB(EA) do { \
    const short8 af0_ = pack8((EA)[0], (EA)[1]); \
    const short8 af1_ = pack8((EA)[2], (EA)[3]); \
    const short8 af2_ = pack8((EA)[4], (EA)[5]); \
    f32x4 acc_[6] = {}; \
    _Pragma("unroll") \
    for (int ct = 0; ct < 6; ++ct) { \
        acc_[ct] = __builtin_amdgcn_mfma_f32_16x16x32_bf16(af0_, \
            *(const short8*)&WsT[(ct * 16 + l15) * 104 + 0 + lg * 8], acc_[ct], 0, 0, 0); \
        acc_[ct] = __builtin_amdgcn_mfma_f32_16x16x32_bf16(af1_, \
            *(const short8*)&WsT[(ct * 16 + l15) * 104 + 32 + lg * 8], acc_[ct], 0, 0, 0); \
        acc_[ct] = __builtin_amdgcn_mfma_f32_16x16x32_bf16(af2_, \
            *(const short8*)&WsT[(ct * 16 + l15) * 104 + 64 + lg * 8], acc_[ct], 0, 0, 0); \
    } \
    _Pragma("unroll") \
    for (int ct = 0; ct < 6; ++ct) { \
        const int col_ = ct * 16 + l15; \
        const float b_ = bes[col_]; \
        _Pragma("unroll") \
        for (int r = 0; r < 4; ++r) \
            myep[(lg * 4 + r) * 104 + col_] = f2bf(acc_[ct][r] + b_); \
    } \
} while (0)

#define ACC3(KU, QU, EU) \
    s_ += bf2f_lo(KU) * bf2f_lo(QU) * bf2f_lo(EU) + \
          bf2f_hi(KU) * bf2f_hi(QU) * bf2f_hi(EU);

#define SCORE_PHASE(KQ, P0, P1) do { \
    _Pragma("unroll") \
    for (int pass_ = 0; pass_ < 2; ++pass_) { \
        const int rl_ = pass_ * 8 + er; \
        const int pos_ = pass_ ? (P1) : (P0); \
        const unsigned short* ep_ = &myep[rl_ * 104 + h * 12]; \
        const uint2 u0_ = *(const uint2*)&ep_[0]; \
        const uint2 u1_ = *(const uint2*)&ep_[4]; \
        const uint2 u2_ = *(const uint2*)&ep_[8]; \
        const uint2 ka_ = (KQ)[pass_ * 6 + 0]; \
        const uint2 kb_ = (KQ)[pass_ * 6 + 1]; \
        const uint2 kc_ = (KQ)[pass_ * 6 + 2]; \
        const uint2 qa_ = (KQ)[pass_ * 6 + 3]; \
        const uint2 qb_ = (KQ)[pass_ * 6 + 4]; \
        const uint2 qc_ = (KQ)[pass_ * 6 + 5]; \
        float s_ = 0.f; \
        ACC3(ka_.x, qa_.x, u0_.x); ACC3(ka_.y, qa_.y, u0_.y); \
        ACC3(kb_.x, qb_.x, u1_.x); ACC3(kb_.y, qb_.y, u1_.y); \
        ACC3(kc_.x, qc_.x, u2_.x); ACC3(kc_.y, qc_.y, u2_.y); \
        s_ *= 0.2886751345948129f; \
        s_ = fminf(fmaxf(s_, -5.f), 5.f); \
        score_s[(size_t)pos_ * 8 + h] = __expf(s_); \
    } \
} while (0)

    int vA, vB;
    float4 eaA[6], eaB[6];
    uint2 kqA[12], kqB[12];
    int pA0 = 0, pA1 = 0, pB0 = 0, pB1 = 0;

    // ---- prologue: issue tile 0 & 1 streaming loads ----
    LOAD_EI(vA, t0);
    LOAD_EA(eaA, t0);
    LOAD_EI(vB, t0 + 1);
    LOAD_EA(eaB, t0 + 1);

    // stage WsT + bias once per block (hides prologue load latency)
    for (int j = t; j < 96 * 12; j += 256) {
        const int c = j / 12, kc = j % 12;
        *(uint4*)&WsT[c * 104 + kc * 8] = *(const uint4*)&WeT[c * 96 + kc * 8];
    }
    if (t < 96) bes[t] = be[t];
    __syncthreads();

    ISSUE_GATHER(vA, kqA, pA0, pA1);   // K/Q for tile 0 (waits on vA)

    #pragma unroll 1
    for (int i = 0; i < TPB; i += 2) {
        // ---- process tile i (A); prefetch i+1 gathers, i+2 streams ----
        MFMA_EPB(eaA);
        ISSUE_GATHER(vB, kqB, pB0, pB1);                 // i+1 <= 9 always
        if (i + 2 < TPB) { LOAD_EI(vA, t0 + i + 2); LOAD_EA(eaA, t0 + i + 2); }
        SCORE_PHASE(kqA, pA0, pA1);

        // ---- process tile i+1 (B); prefetch i+2 gathers, i+3 streams ----
        MFMA_EPB(eaB);
        if (i + 2 < TPB) ISSUE_GATHER(vA, kqA, pA0, pA1);
        if (i + 3 < TPB) { LOAD_EI(vB, t0 + i + 3); LOAD_EA(eaB, t0 + i + 3); }
        SCORE_PHASE(kqB, pB0, pB1);
    }

#undef LOAD_EI
#undef LOAD_EA
#undef ISSUE_GATHER
#undef MFMA_EPB
#undef ACC3
#undef SCORE_PHASE
}

// ---------------------------------------------------------------------------
// Gather kernel: thread = (node, 24-col group g).
// ---------------------------------------------------------------------------
__global__ __launch_bounds__(256) void gather_kernel(
    const int* __restrict__ offsets, const int* __restrict__ sorted_src,
    const float* __restrict__ score_s, const unsigned short* __restrict__ Vb,
    float* __restrict__ out)
{
    const int gid = blockIdx.x * 256 + threadIdx.x;
    if (gid >= N_NODES * 4) return;
    const int n = gid >> 2;
    const int g = gid & 3;           // cols g*24 .. g*24+23, heads 2g, 2g+1

    const int s0 = offsets[n];
    const int s1 = offsets[n + 1];

    float acc[24];
    #pragma unroll
    for (int i = 0; i < 24; ++i) acc[i] = 0.f;
    float z0 = 0.f, z1 = 0.f;

#define ACCUM(U0, U1, U2, SC) \
    acc[0]  += SC.x * bf2f_lo(U0.x); acc[1]  += SC.x * bf2f_hi(U0.x); \
    acc[2]  += SC.x * bf2f_lo(U0.y); acc[3]  += SC.x * bf2f_hi(U0.y); \
    acc[4]  += SC.x * bf2f_lo(U0.z); acc[5]  += SC.x * bf2f_hi(U0.z); \
    acc[6]  += SC.x * bf2f_lo(U0.w); acc[7]  += SC.x * bf2f_hi(U0.w); \
    acc[8]  += SC.x * bf2f_lo(U1.x); acc[9]  += SC.x * bf2f_hi(U1.x); \
    acc[10] += SC.x * bf2f_lo(U1.y); acc[11] += SC.x * bf2f_hi(U1.y); \
    acc[12] += SC.y * bf2f_lo(U1.z); acc[13] += SC.y * bf2f_hi(U1.z); \
    acc[14] += SC.y * bf2f_lo(U1.w); acc[15] += SC.y * bf2f_hi(U1.w); \
    acc[16] += SC.y * bf2f_lo(U2.x); acc[17] += SC.y * bf2f_hi(U2.x); \
    acc[18] += SC.y * bf2f_lo(U2.y); acc[19] += SC.y * bf2f_hi(U2.y); \
    acc[20] += SC.y * bf2f_lo(U2.z); acc[21] += SC.y * bf2f_hi(U2.z); \
    acc[22] += SC.y * bf2f_lo(U2.w); acc[23] += SC.y * bf2f_hi(U2.w);

    int p = s0;
    for (; p + 2 <= s1; p += 2) {
        const int srcA = sorted_src[p];
        const int srcB = sorted_src[p + 1];
        const float2 scA = *(const float2*)&score_s[(size_t)p * 8 + g * 2];
        const float2 scB = *(const float2*)&score_s[(size_t)(p + 1) * 8 + g * 2];
        const uint4* VA = (const uint4*)&Vb[(size_t)srcA * 96 + g * 24];
        const uint4* VB = (const uint4*)&Vb[(size_t)srcB * 96 + g * 24];
        const uint4 a0 = VA[0], a1 = VA[1], a2 = VA[2];
        const uint4 b0 = VB[0], b1 = VB[1], b2 = VB[2];
        ACCUM(a0, a1, a2, scA);
        ACCUM(b0, b1, b2, scB);
        z0 += scA.x + scB.x;
        z1 += scA.y + scB.y;
    }
    if (p < s1) {
        const int srcA = sorted_src[p];
        const float2 scA = *(const float2*)&score_s[(size_t)p * 8 + g * 2];
        const uint4* VA = (const uint4*)&Vb[(size_t)srcA * 96 + g * 24];
        const uint4 a0 = VA[0], a1 = VA[1], a2 = VA[2];
        ACCUM(a0, a1, a2, scA);
        z0 += scA.x;
        z1 += scA.y;
    }
#undef ACCUM

    const float i0 = 1.f / (z0 + 1e-6f);
    const float i1 = 1.f / (z1 + 1e-6f);
    float o[24];
    #pragma unroll
    for (int k = 0; k < 24; ++k) o[k] = acc[k] * (k < 12 ? i0 : i1);
    float* dst = &out[(size_t)n * 96 + g * 24];
    #pragma unroll
    for (int k = 0; k < 6; ++k)
        *(float4*)&dst[k * 4] = make_float4(o[k*4], o[k*4+1], o[k*4+2], o[k*4+3]);
}

// ---------------------------------------------------------------------------
extern "C" void kernel_launch(void* const* d_in, const int* in_sizes, int n_in,
                              void* d_out, int out_size, void* d_ws, size_t ws_size,
                              hipStream_t stream) {
    const float* x  = (const float*)d_in[0];
    const int*   ei = (const int*)d_in[1];   // [2, E] int32 (JAX x64 disabled)
    const float* ea = (const float*)d_in[2];
    const float* Wq = (const float*)d_in[3];
    const float* bq = (const float*)d_in[4];
    const float* Wk = (const float*)d_in[5];
    const float* bk = (const float*)d_in[6];
    const float* We = (const float*)d_in[7];
    const float* be = (const float*)d_in[8];
    const float* Wv = (const float*)d_in[9];
    const float* bv = (const float*)d_in[10];

    float* out = (float*)d_out;

    // workspace: Qb | Kb | Vb | score_s | offsets | cursor | sorted_src |
    //            WeT | WqT | WkT | WvT | partial
    const size_t nqkv = (size_t)N_NODES * 96;
    unsigned short* Qb = (unsigned short*)d_ws;
    unsigned short* Kb = Qb + nqkv;
    unsigned short* Vb = Kb + nqkv;
    float* score_s  = (float*)(Vb + nqkv);                   // [E,8]
    int* offsets    = (int*)(score_s + (size_t)N_EDGES * 8); // [N+1]
    int* cursor     = offsets + (N_NODES + 1);               // [N]
    int* sorted_src = cursor + N_NODES;                      // [E]
    unsigned short* WeT = (unsigned short*)(sorted_src + N_EDGES);  // [96*96]
    unsigned short* WqT = WeT + 9216;
    unsigned short* WkT = WqT + 9216;
    unsigned short* WvT = WkT + 9216;
    int* partial = (int*)(WvT + 9216);                       // [256]

    hipMemsetAsync(cursor, 0, N_NODES * sizeof(int), stream);

    wet4_kernel<<<dim3(144), 256, 0, stream>>>(
        Wq, Wk, Wv, We, WqT, WkT, WvT, WeT);

    prep_kernel<<<dim3(QKV_BLOCKS + HIST_BLOCKS), 256, 0, stream>>>(
        x, bq, bk, bv, WqT, WkT, WvT, ei, Qb, Kb, Vb, cursor);

    scanA_kernel<<<dim3(SCAN_BLOCKS), 256, 0, stream>>>(cursor, partial);
    scanB_kernel<<<dim3(1), 256, 0, stream>>>(partial, offsets);
    scanC_kernel<<<dim3(SCAN_BLOCKS), 256, 0, stream>>>(cursor, partial, offsets);

    score_kernel<<<dim3(SCORE_GRID), 256, 0, stream>>>(
        ea, ei, WeT, be, Qb, Kb, cursor, sorted_src, score_s);

    gather_kernel<<<dim3((N_NODES * 4 + 255) / 256), 256, 0, stream>>>(
        offsets, sorted_src, score_s, Vb, out);
}